// Round 23
// baseline (196.005 us; speedup 1.0000x reference)
//
#include <hip/hip_runtime.h>
#include <stdint.h>

// 2-layer tanh RNN, fused, f32. R23 = R18's asm-scheduled counted-lgkmcnt
// pipeline x R16's (1,1) geometry.
//   - waves_per_eu(1,1): only config where RA exceeds ~104 VGPR (R16/R21:
//     132 resident). Grid 1024 blocks = exactly 1 wave/SIMD, all resident.
//   - GB=4 batches/wave, 2 adjacent rows/lane (40 lanes, 120 weight scalars).
//   - In-loop LDS ONLY in asm blocks: A{2x ds_write_b32 h0[i], 5x
//     ds_read_b128 h0-state, 1x ds_read_b32 x[i+1]} = 8 ops; B{2 writes
//     h1[i-1], 5 reads h1-state} = 7 ops. Counted waits: mid lgkmcnt(8)
//     (prev B done -> d valid), end lgkmcnt(7) (A done -> c, xt valid).
//     Reads stay in flight under the other layer's dots+tanh.
//   - sched_barrier(0) after each wait (rule 18); no memory clobbers
//     in-loop (no C++ memory ops in loop); fences at prologue/epilogue.

#define Bsz 4096
#define Tn  512
#define Hn  20
#define GB  4
#define LPB 10
#define XPAD 520
#define NTHREADS 64

typedef float v2 __attribute__((ext_vector_type(2)));

__device__ __forceinline__ float tanh_fast(float v) {
    float e = __expf(2.0f * v);
    return 1.0f - 2.0f * __builtin_amdgcn_rcpf(e + 1.0f);
}

// 20-dot of v2-weight row against float4-quartered state, 2 chains
#define DOT20Q(acc, accb, W, C0, C1, C2, C3, C4) do { \
    acc  = __builtin_elementwise_fma(W##0, (v2){(C0).x,(C0).y}, acc);  \
    accb = __builtin_elementwise_fma(W##1, (v2){(C0).z,(C0).w}, accb); \
    acc  = __builtin_elementwise_fma(W##2, (v2){(C1).x,(C1).y}, acc);  \
    accb = __builtin_elementwise_fma(W##3, (v2){(C1).z,(C1).w}, accb); \
    acc  = __builtin_elementwise_fma(W##4, (v2){(C2).x,(C2).y}, acc);  \
    accb = __builtin_elementwise_fma(W##5, (v2){(C2).z,(C2).w}, accb); \
    acc  = __builtin_elementwise_fma(W##6, (v2){(C3).x,(C3).y}, acc);  \
    accb = __builtin_elementwise_fma(W##7, (v2){(C3).z,(C3).w}, accb); \
    acc  = __builtin_elementwise_fma(W##8, (v2){(C4).x,(C4).y}, acc);  \
    accb = __builtin_elementwise_fma(W##9, (v2){(C4).z,(C4).w}, accb); \
} while (0)

#define LOAD_ROWP(W, ptr) \
    v2 W##0, W##1, W##2, W##3, W##4, W##5, W##6, W##7, W##8, W##9; \
    { const float4* _p = (const float4*)(ptr); \
      float4 _t; \
      _t = _p[0]; W##0 = (v2){_t.x, _t.y}; W##1 = (v2){_t.z, _t.w}; \
      _t = _p[1]; W##2 = (v2){_t.x, _t.y}; W##3 = (v2){_t.z, _t.w}; \
      _t = _p[2]; W##4 = (v2){_t.x, _t.y}; W##5 = (v2){_t.z, _t.w}; \
      _t = _p[3]; W##6 = (v2){_t.x, _t.y}; W##7 = (v2){_t.z, _t.w}; \
      _t = _p[4]; W##8 = (v2){_t.x, _t.y}; W##9 = (v2){_t.z, _t.w}; }

__global__ __launch_bounds__(NTHREADS)
__attribute__((amdgpu_waves_per_eu(1, 1)))
void rnn2_fused(const float* __restrict__ x,        // [B,T,1]
                const float* __restrict__ hidden,   // [2,B,H]
                const float* __restrict__ W_ih0,    // [H,1]
                const float* __restrict__ W_hh0,    // [H,H]
                const float* __restrict__ b_ih0,    // [H]
                const float* __restrict__ b_hh0,    // [H]
                const float* __restrict__ W_ih1,    // [H,H]
                const float* __restrict__ W_hh1,    // [H,H]
                const float* __restrict__ b_ih1,    // [H]
                const float* __restrict__ b_hh1,    // [H]
                const float* __restrict__ fc_w,     // [1,H]
                const float* __restrict__ fc_b,     // [1]
                float* __restrict__ out)            // [B] ++ [2,B,H] flat
{
    const int tid = threadIdx.x;
    const int jj  = tid % LPB;                 // 0..9
    int g = tid / LPB;                         // 0..6
    if (g >= GB) g = GB - 1;                   // lanes 40..63 dup batch 3
                                               // (same addr+data: benign)
    const int j0 = 2 * jj;
    const int b  = blockIdx.x * GB + g;        // 4096 = 1024*4: always valid
    const bool store_ok = (tid < GB * LPB);

    __shared__ __align__(16) float xs[GB][XPAD];   // 8.3 KB
    __shared__ __align__(16) float hs[2][GB][Hn];  // state mailboxes

    // ---- weights: rows j0, j0+1 of the 3 HxH mats (120 scalars, resident
    // under the (1,1) 512-reg budget -- the R16-verified unlock)
    LOAD_ROWP(w0e, W_hh0 + j0 * Hn)
    LOAD_ROWP(w0o, W_hh0 + (j0 + 1) * Hn)
    LOAD_ROWP(w1e, W_ih1 + j0 * Hn)
    LOAD_ROWP(w1o, W_ih1 + (j0 + 1) * Hn)
    LOAD_ROWP(w2e, W_hh1 + j0 * Hn)
    LOAD_ROWP(w2o, W_hh1 + (j0 + 1) * Hn)

    const float wih0e = W_ih0[j0],  wih0o = W_ih0[j0 + 1];
    const float b0e = b_ih0[j0]     + b_hh0[j0];
    const float b0o = b_ih0[j0 + 1] + b_hh0[j0 + 1];
    const float b1e = b_ih1[j0]     + b_hh1[j0];
    const float b1o = b_ih1[j0 + 1] + b_hh1[j0 + 1];

    // ---- stage ALL x (coalesced float4; exact divisibility)
    {
        const int bB = blockIdx.x * GB;
        #pragma unroll
        for (int r = 0; r < (GB * Tn) / (NTHREADS * 4); ++r) {  // 8 rounds
            const int c  = (r * NTHREADS + tid) * 4;
            const int gg = c >> 9;
            const int t  = c & (Tn - 1);
            float4 v = *(const float4*)(x + (long)(bB + gg) * Tn + t);
            *(float4*)&xs[gg][t] = v;
        }
    }

    // ---- init state (C++; fenced by the drain below)
    *(float2*)&hs[0][g][j0] = *(const float2*)(hidden + (long)b * Hn + j0);
    *(float2*)&hs[1][g][j0] =
        *(const float2*)(hidden + (long)Bsz * Hn + (long)b * Hn + j0);

    // ---- prologue: h0[0] in C++ (in-order DS: reads see init writes)
    float n0e, n0o;
    {
        const float4 p0 = *(const float4*)&hs[0][g][0];
        const float4 p1 = *(const float4*)&hs[0][g][4];
        const float4 p2 = *(const float4*)&hs[0][g][8];
        const float4 p3 = *(const float4*)&hs[0][g][12];
        const float4 p4 = *(const float4*)&hs[0][g][16];
        const float xt0 = xs[g][0];
        v2 ae = (v2){fmaf(xt0, wih0e, b0e), 0.f}, aeb = (v2){0.f, 0.f};
        v2 ao = (v2){fmaf(xt0, wih0o, b0o), 0.f}, aob = (v2){0.f, 0.f};
        DOT20Q(ae, aeb, w0e, p0, p1, p2, p3, p4);
        DOT20Q(ao, aob, w0o, p0, p1, p2, p3, p4);
        const v2 se = ae + aeb, so = ao + aob;
        n0e = tanh_fast(se.x + se.y);
        n0o = tanh_fast(so.x + so.y);
    }

    // drain all compiler DS/SMEM ops so counted waits are exact
    asm volatile("s_waitcnt lgkmcnt(0)" ::: "memory");
    __builtin_amdgcn_sched_barrier(0);

    const uint32_t h0_base = (uint32_t)(uintptr_t)&hs[0][g][0];
    const uint32_t h0_w0   = (uint32_t)(uintptr_t)&hs[0][g][j0];
    const uint32_t h0_w1   = (uint32_t)(uintptr_t)&hs[0][g][j0 + 1];
    const uint32_t h1_base = (uint32_t)(uintptr_t)&hs[1][g][0];
    const uint32_t h1_w0   = (uint32_t)(uintptr_t)&hs[1][g][j0];
    const uint32_t h1_w1   = (uint32_t)(uintptr_t)&hs[1][g][j0 + 1];
    uint32_t x_addr        = (uint32_t)(uintptr_t)&xs[g][2];  // iter1 reads x[2]

    float4 c0, c1, c2, c3, c4;   // h0-state broadcast carry
    float4 d0, d1, d2, d3, d4;   // h1-state broadcast carry
    float  xt;

    // preA (8): write h0[0] (2x b32); read h0-state (5x b128); read x[1]
    asm volatile(
        "ds_write_b32 %7, %9\n\t"
        "ds_write_b32 %8, %10\n\t"
        "ds_read_b128 %0, %6 offset:0\n\t"
        "ds_read_b128 %1, %6 offset:16\n\t"
        "ds_read_b128 %2, %6 offset:32\n\t"
        "ds_read_b128 %3, %6 offset:48\n\t"
        "ds_read_b128 %4, %6 offset:64\n\t"
        "ds_read_b32  %5, %11\n\t"
        : "=&v"(c0), "=&v"(c1), "=&v"(c2), "=&v"(c3), "=&v"(c4), "=&v"(xt)
        : "v"(h0_base), "v"(h0_w0), "v"(h0_w1), "v"(n0e), "v"(n0o),
          "v"((uint32_t)(uintptr_t)&xs[g][1]));
    // preB (5): read h1[-1] state
    asm volatile(
        "ds_read_b128 %0, %5 offset:0\n\t"
        "ds_read_b128 %1, %5 offset:16\n\t"
        "ds_read_b128 %2, %5 offset:32\n\t"
        "ds_read_b128 %3, %5 offset:48\n\t"
        "ds_read_b128 %4, %5 offset:64\n\t"
        : "=&v"(d0), "=&v"(d1), "=&v"(d2), "=&v"(d3), "=&v"(d4)
        : "v"(h1_base));
    asm volatile("s_waitcnt lgkmcnt(5)");   // preA done: c = h0[0], xt = x[1]
    __builtin_amdgcn_sched_barrier(0);

    // ---- main loop i=1..511: entry c=h0[i-1] (valid), d=h1[i-2] (in
    // flight, validated by mid-wait). Computes h0[i], h1[i-1].
    #pragma unroll 1
    for (int i = 1; i < Tn; ++i) {
        // region A: layer0 + layer1-input dots (use OLD c), tanh0, asmA
        v2 a0e = (v2){fmaf(xt, wih0e, b0e), 0.f}, a0eb = (v2){0.f, 0.f};
        v2 a0o = (v2){fmaf(xt, wih0o, b0o), 0.f}, a0ob = (v2){0.f, 0.f};
        v2 a1e = (v2){b1e, 0.f}, a1eb = (v2){0.f, 0.f};
        v2 a1o = (v2){b1o, 0.f}, a1ob = (v2){0.f, 0.f};
        DOT20Q(a0e, a0eb, w0e, c0, c1, c2, c3, c4);
        DOT20Q(a0o, a0ob, w0o, c0, c1, c2, c3, c4);
        DOT20Q(a1e, a1eb, w1e, c0, c1, c2, c3, c4);
        DOT20Q(a1o, a1ob, w1o, c0, c1, c2, c3, c4);
        const v2 s0e = a0e + a0eb, s0o = a0o + a0ob;
        n0e = tanh_fast(s0e.x + s0e.y);
        n0o = tanh_fast(s0o.x + s0o.y);

        asm volatile(   // A (8): write h0[i]; read back state; read x[i+1]
            "ds_write_b32 %7, %9\n\t"
            "ds_write_b32 %8, %10\n\t"
            "ds_read_b128 %0, %6 offset:0\n\t"
            "ds_read_b128 %1, %6 offset:16\n\t"
            "ds_read_b128 %2, %6 offset:32\n\t"
            "ds_read_b128 %3, %6 offset:48\n\t"
            "ds_read_b128 %4, %6 offset:64\n\t"
            "ds_read_b32  %5, %11\n\t"
            : "=&v"(c0), "=&v"(c1), "=&v"(c2), "=&v"(c3), "=&v"(c4), "=&v"(xt)
            : "v"(h0_base), "v"(h0_w0), "v"(h0_w1), "v"(n0e), "v"(n0o),
              "v"(x_addr));
        x_addr += 4;

        asm volatile("s_waitcnt lgkmcnt(8)");   // prev B done: d valid
        __builtin_amdgcn_sched_barrier(0);

        // region B: layer1 recurrent dot (uses d), tanh1, asmB
        v2 a2e = (v2){0.f, 0.f}, a2eb = (v2){0.f, 0.f};
        v2 a2o = (v2){0.f, 0.f}, a2ob = (v2){0.f, 0.f};
        DOT20Q(a2e, a2eb, w2e, d0, d1, d2, d3, d4);
        DOT20Q(a2o, a2ob, w2o, d0, d1, d2, d3, d4);
        const v2 s1e = (a1e + a1eb) + (a2e + a2eb);
        const v2 s1o = (a1o + a1ob) + (a2o + a2ob);
        const float n1e = tanh_fast(s1e.x + s1e.y);
        const float n1o = tanh_fast(s1o.x + s1o.y);

        asm volatile(   // B (7): write h1[i-1]; read back state
            "ds_write_b32 %5, %7\n\t"
            "ds_write_b32 %6, %8\n\t"
            "ds_read_b128 %0, %9 offset:0\n\t"
            "ds_read_b128 %1, %9 offset:16\n\t"
            "ds_read_b128 %2, %9 offset:32\n\t"
            "ds_read_b128 %3, %9 offset:48\n\t"
            "ds_read_b128 %4, %9 offset:64\n\t"
            : "=&v"(d0), "=&v"(d1), "=&v"(d2), "=&v"(d3), "=&v"(d4)
            : "v"(h1_w0), "v"(h1_w1), "v"(n1e), "v"(n1o), "v"(h1_base));

        asm volatile("s_waitcnt lgkmcnt(7)");   // A done: c, xt valid
        __builtin_amdgcn_sched_barrier(0);
    }

    // ---- epilogue: drain; h1[511] from c=h0[511], d=h1[510]
    asm volatile("s_waitcnt lgkmcnt(0)" ::: "memory");
    __builtin_amdgcn_sched_barrier(0);
    float n1e, n1o;
    {
        v2 a1e = (v2){b1e, 0.f}, a1eb = (v2){0.f, 0.f};
        v2 a1o = (v2){b1o, 0.f}, a1ob = (v2){0.f, 0.f};
        v2 a2e = (v2){0.f, 0.f}, a2eb = (v2){0.f, 0.f};
        v2 a2o = (v2){0.f, 0.f}, a2ob = (v2){0.f, 0.f};
        DOT20Q(a1e, a1eb, w1e, c0, c1, c2, c3, c4);
        DOT20Q(a1o, a1ob, w1o, c0, c1, c2, c3, c4);
        DOT20Q(a2e, a2eb, w2e, d0, d1, d2, d3, d4);
        DOT20Q(a2o, a2ob, w2o, d0, d1, d2, d3, d4);
        const v2 s1e = (a1e + a1eb) + (a2e + a2eb);
        const v2 s1o = (a1o + a1ob) + (a2o + a2ob);
        n1e = tanh_fast(s1e.x + s1e.y);
        n1o = tanh_fast(s1o.x + s1o.y);
    }
    // publish h1[511] for the fc gather (C++, after the memory fence)
    *(float2*)&hs[1][g][j0] = make_float2(n1e, n1o);

    // ---- outputs: n0e/n0o = h0[511] rows j0/j0+1; n1e/n1o = h1[511]
    if (store_ok) {
        out[Bsz + (long)b * Hn + j0]     = n0e;
        out[Bsz + (long)b * Hn + j0 + 1] = n0o;
        out[Bsz + (long)Bsz * Hn + (long)b * Hn + j0]     = n1e;
        out[Bsz + (long)Bsz * Hn + (long)b * Hn + j0 + 1] = n1o;
        if (jj == 0) {                 // fc head: one lane per batch
            LOAD_ROWP(fw, fc_w)
            const float4 v0 = *(const float4*)&hs[1][g][0];
            const float4 v1 = *(const float4*)&hs[1][g][4];
            const float4 v2q = *(const float4*)&hs[1][g][8];
            const float4 v3 = *(const float4*)&hs[1][g][12];
            const float4 v4 = *(const float4*)&hs[1][g][16];
            v2 aA = (v2){fc_b[0], 0.f};
            v2 aB = (v2){0.f, 0.f};
            DOT20Q(aA, aB, fw, v0, v1, v2q, v3, v4);
            const v2 s = aA + aB;
            out[b] = s.x + s.y;
        }
    }
}

extern "C" void kernel_launch(void* const* d_in, const int* in_sizes, int n_in,
                              void* d_out, int out_size, void* d_ws, size_t ws_size,
                              hipStream_t stream) {
    const float* x      = (const float*)d_in[0];
    const float* hidden = (const float*)d_in[1];
    const float* W_ih0  = (const float*)d_in[2];
    const float* W_hh0  = (const float*)d_in[3];
    const float* b_ih0  = (const float*)d_in[4];
    const float* b_hh0  = (const float*)d_in[5];
    const float* W_ih1  = (const float*)d_in[6];
    const float* W_hh1  = (const float*)d_in[7];
    const float* b_ih1  = (const float*)d_in[8];
    const float* b_hh1  = (const float*)d_in[9];
    const float* fc_w   = (const float*)d_in[10];
    const float* fc_b   = (const float*)d_in[11];

    rnn2_fused<<<Bsz / GB, NTHREADS, 0, stream>>>(   // 1024 blocks
        x, hidden, W_ih0, W_hh0, b_ih0, b_hh0,
        W_ih1, W_hh1, b_ih1, b_hh1, fc_w, fc_b, (float*)d_out);
}

// Round 24
// 167.795 us; speedup vs baseline: 1.1681x; 1.1681x over previous
//
#include <hip/hip_runtime.h>

// 2-layer tanh RNN, fused, f32, single-wave blocks, no barriers,
// single-buffer LDS state, packed-f32 math, unroll-4. B=4096,T=512,H=20.
// R24 = R14 (129.4us, best simple variant) with ONE knob changed:
//   waves_per_eu(1,2) -> (1,1). RA budget 256 -> 512 VGPRs.
//   R12-R22 showed the allocator refuses weight residency at (1,2)
//   (VGPR pinned 88-104 => ~15 weight reloads + vmcnt waits per iter on
//   both issue stream and dependence chain); (1,1) is the only config
//   that unlocked it (R16/R23: VGPR=132). Hardware occupancy follows
//   actual VGPR use (~160 -> up to 3 waves/SIMD), so the 1366-wave
//   placement is unchanged -- clean A/B on residency alone.

#define Bsz 4096
#define Tn  512
#define Hn  20
#define GB  3
#define XPAD 520               // x row stride: groups 8 banks apart
#define NTHREADS 64

typedef float v2 __attribute__((ext_vector_type(2)));

__device__ __forceinline__ float tanh_fast(float v) {
    // tanh(v) = 1 - 2/(exp(2v)+1); v_exp_f32 + v_rcp_f32.
    float e = __expf(2.0f * v);
    return 1.0f - 2.0f * __builtin_amdgcn_rcpf(e + 1.0f);
}

// packed 20-dot: 10 v_pk_fma_f32 over two packed accumulator chains.
#define DOT20P(acc, accb, W, H) do { \
    acc  = __builtin_elementwise_fma(W##0, H##0, acc);  \
    accb = __builtin_elementwise_fma(W##1, H##1, accb); \
    acc  = __builtin_elementwise_fma(W##2, H##2, acc);  \
    accb = __builtin_elementwise_fma(W##3, H##3, accb); \
    acc  = __builtin_elementwise_fma(W##4, H##4, acc);  \
    accb = __builtin_elementwise_fma(W##5, H##5, accb); \
    acc  = __builtin_elementwise_fma(W##6, H##6, acc);  \
    accb = __builtin_elementwise_fma(W##7, H##7, accb); \
    acc  = __builtin_elementwise_fma(W##8, H##8, acc);  \
    accb = __builtin_elementwise_fma(W##9, H##9, accb); \
} while (0)

// load one H=20 row as 10 named v2 SSA values (via float4 vector loads)
#define LOAD_ROWP(W, ptr) \
    v2 W##0, W##1, W##2, W##3, W##4, W##5, W##6, W##7, W##8, W##9; \
    { const float4* _p = (const float4*)(ptr); \
      float4 _t; \
      _t = _p[0]; W##0 = (v2){_t.x, _t.y}; W##1 = (v2){_t.z, _t.w}; \
      _t = _p[1]; W##2 = (v2){_t.x, _t.y}; W##3 = (v2){_t.z, _t.w}; \
      _t = _p[2]; W##4 = (v2){_t.x, _t.y}; W##5 = (v2){_t.z, _t.w}; \
      _t = _p[3]; W##6 = (v2){_t.x, _t.y}; W##7 = (v2){_t.z, _t.w}; \
      _t = _p[4]; W##8 = (v2){_t.x, _t.y}; W##9 = (v2){_t.z, _t.w}; }

// read h-state tile (LDS, broadcast b128) into 10 named v2 values
#define READ_H(H, base) \
    v2 H##0, H##1, H##2, H##3, H##4, H##5, H##6, H##7, H##8, H##9; \
    { const float4 _a = *(const float4*)((base) + 0);  \
      const float4 _b = *(const float4*)((base) + 4);  \
      const float4 _c = *(const float4*)((base) + 8);  \
      const float4 _d = *(const float4*)((base) + 12); \
      const float4 _e = *(const float4*)((base) + 16); \
      H##0 = (v2){_a.x, _a.y}; H##1 = (v2){_a.z, _a.w}; \
      H##2 = (v2){_b.x, _b.y}; H##3 = (v2){_b.z, _b.w}; \
      H##4 = (v2){_c.x, _c.y}; H##5 = (v2){_c.z, _c.w}; \
      H##6 = (v2){_d.x, _d.y}; H##7 = (v2){_d.z, _d.w}; \
      H##8 = (v2){_e.x, _e.y}; H##9 = (v2){_e.z, _e.w}; }

__global__ __launch_bounds__(NTHREADS)
__attribute__((amdgpu_waves_per_eu(1, 1)))
void rnn2_fused(const float* __restrict__ x,        // [B,T,1]
                const float* __restrict__ hidden,   // [2,B,H]
                const float* __restrict__ W_ih0,    // [H,1]
                const float* __restrict__ W_hh0,    // [H,H]
                const float* __restrict__ b_ih0,    // [H]
                const float* __restrict__ b_hh0,    // [H]
                const float* __restrict__ W_ih1,    // [H,H]
                const float* __restrict__ W_hh1,    // [H,H]
                const float* __restrict__ b_ih1,    // [H]
                const float* __restrict__ b_hh1,    // [H]
                const float* __restrict__ fc_w,     // [1,H]
                const float* __restrict__ fc_b,     // [1]
                float* __restrict__ out)            // [B] ++ [2,B,H] flat
{
    const int tid = threadIdx.x;
    int g = tid / Hn;                  // 0..3
    int j = tid - g * Hn;              // 0..19 (0..3 for tid>=60)
    const bool lane_ok = (tid < GB * Hn);
    if (!lane_ok) g = GB - 1;          // lanes 60..63 dup batch 2, j=0..3
                                       // (same-addr same-data writes: benign)
    const int  b        = blockIdx.x * GB + g;
    const bool b_ok     = (b < Bsz);
    const int  bl       = b_ok ? b : (Bsz - 1);
    const bool store_ok = lane_ok && b_ok;

    __shared__ float xs[GB][XPAD];     // 6.24 KB
    __shared__ float hs[2][GB][Hn];    // single-buffer state [layer][g][j]

    // ---- per-lane weight rows as 30 named v2 SSA values (loop-invariant)
    LOAD_ROWP(w0, W_hh0 + j * Hn)      // layer0 recurrent row j
    LOAD_ROWP(w1, W_ih1 + j * Hn)      // layer1 input row j
    LOAD_ROWP(w2, W_hh1 + j * Hn)      // layer1 recurrent row j

    const float wih0  = W_ih0[j];
    const float bias0 = b_ih0[j] + b_hh0[j];
    const float bias1 = b_ih1[j] + b_hh1[j];

    // ---- stage ALL x (coalesced float4; clamped batch rows)
    {
        const int bB = blockIdx.x * GB;
        #pragma unroll
        for (int r = 0; r < (GB * Tn) / (NTHREADS * 4); ++r) {  // 6 rounds
            const int c  = (r * NTHREADS + tid) * 4;
            const int gg = c >> 9;            // c / 512
            const int t  = c & (Tn - 1);      // c % 512
            const int bb = (bB + gg < Bsz) ? (bB + gg) : (Bsz - 1);
            float4 v = *(const float4*)(x + (long)bb * Tn + t);
            *(float4*)&xs[gg][t] = v;
        }
    }

    // ---- init state: hs[0] = h0[-1], hs[1] = h1[-1]
    hs[0][g][j] = hidden[bl * Hn + j];
    hs[1][g][j] = hidden[(long)Bsz * Hn + bl * Hn + j];
    // single-wave in-order DS pipe: later reads see these writes

    // ---- prologue (i=0): h0[0] = tanh(W_hh0 h0[-1] + x0 wih0 + b0)
    {
        READ_H(hA, &hs[0][g][0])
        v2 a0  = (v2){fmaf(xs[g][0], wih0, bias0), 0.f};
        v2 a0b = (v2){0.f, 0.f};
        DOT20P(a0, a0b, w0, hA);
        v2 s0 = a0 + a0b;
        hs[0][g][j] = tanh_fast(s0.x + s0.y);
    }

    // ---- main loop i=1..511: entry: hs[0]=h0[i-1], hs[1]=h1[i-2].
    // computes h0[i], h1[i-1]; writes both. Unroll-4 pipeline window.
    #pragma unroll 4
    for (int i = 1; i < Tn; ++i) {
        READ_H(hA, &hs[0][g][0])
        READ_H(hB, &hs[1][g][0])

        const float xt = xs[g][i];

        v2 a0  = (v2){fmaf(xt, wih0, bias0), 0.f};
        v2 a0b = (v2){0.f, 0.f};
        v2 a1  = (v2){bias1, 0.f};
        v2 a1b = (v2){0.f, 0.f};
        v2 a2  = (v2){0.f, 0.f};
        v2 a2b = (v2){0.f, 0.f};
        DOT20P(a0, a0b, w0, hA);
        DOT20P(a1, a1b, w1, hA);
        DOT20P(a2, a2b, w2, hB);

        const v2 s0 = a0 + a0b;
        const v2 s1 = (a1 + a1b) + (a2 + a2b);
        const float n0 = tanh_fast(s0.x + s0.y);
        const float n1 = tanh_fast(s1.x + s1.y);
        hs[0][g][j] = n0;   // h0[i]
        hs[1][g][j] = n1;   // h1[i-1]
    }

    // ---- epilogue (i=512): h1[511] from h0[511], h1[510]
    {
        READ_H(hA, &hs[0][g][0])
        READ_H(hB, &hs[1][g][0])
        v2 a1  = (v2){bias1, 0.f};
        v2 a1b = (v2){0.f, 0.f};
        v2 a2  = (v2){0.f, 0.f};
        v2 a2b = (v2){0.f, 0.f};
        DOT20P(a1, a1b, w1, hA);
        DOT20P(a2, a2b, w2, hB);
        const v2 s1 = (a1 + a1b) + (a2 + a2b);
        hs[1][g][j] = tanh_fast(s1.x + s1.y);
    }

    // ---- outputs: hs[0]=h0[511], hs[1]=h1[511]
    if (store_ok) {
        out[Bsz + (long)b * Hn + j]                  = hs[0][g][j];  // new_hidden[0]
        out[Bsz + (long)Bsz * Hn + (long)b * Hn + j] = hs[1][g][j];  // new_hidden[1]
        if (j == 0) {                  // fc head: one lane per batch
            LOAD_ROWP(fw, fc_w)
            READ_H(hv, &hs[1][g][0])
            v2 aA = (v2){fc_b[0], 0.f};
            v2 aB = (v2){0.f, 0.f};
            DOT20P(aA, aB, fw, hv);
            const v2 s = aA + aB;
            out[b] = s.x + s.y;
        }
    }
}

extern "C" void kernel_launch(void* const* d_in, const int* in_sizes, int n_in,
                              void* d_out, int out_size, void* d_ws, size_t ws_size,
                              hipStream_t stream) {
    const float* x      = (const float*)d_in[0];
    const float* hidden = (const float*)d_in[1];
    const float* W_ih0  = (const float*)d_in[2];
    const float* W_hh0  = (const float*)d_in[3];
    const float* b_ih0  = (const float*)d_in[4];
    const float* b_hh0  = (const float*)d_in[5];
    const float* W_ih1  = (const float*)d_in[6];
    const float* W_hh1  = (const float*)d_in[7];
    const float* b_ih1  = (const float*)d_in[8];
    const float* b_hh1  = (const float*)d_in[9];
    const float* fc_w   = (const float*)d_in[10];
    const float* fc_b   = (const float*)d_in[11];

    const int nblocks = (Bsz + GB - 1) / GB;   // 1366
    rnn2_fused<<<nblocks, NTHREADS, 0, stream>>>(
        x, hidden, W_ih0, W_hh0, b_ih0, b_hh0,
        W_ih1, W_hh1, b_ih1, b_hh1, fc_w, fc_b, (float*)d_out);
}

// Round 25
// 127.670 us; speedup vs baseline: 1.5353x; 1.3143x over previous
//
#include <hip/hip_runtime.h>

// 2-layer tanh RNN, fused, f32. R25 = R20's phased producer-consumer
// x R24's residency discovery x exact-fit grid.
//  - waves_per_eu(1,1): only config where weights go VGPR-resident
//    (R16/R23/R24: VGPR=132). Caveat (R24): it also caps runtime occupancy
//    at 1 wave/EU -> grid MUST be <=1024 waves. Here: 512 blocks x 2 = 1024.
//  - GB=8 batches/block; 8 lanes/batch; 3 row-slots/lane (jj, jj+8,
//    min(jj+16,19); clamped dup lanes recompute row 19 bit-identically ->
//    same-addr same-data writes, benign).
//  - wave0 = layer0 only (3 dots); wave1 = layer1 (6 dots), one phase
//    behind, h0 via 16-slot LDS ring, barrier once per K=8 steps.
//  - wave1's h0-ring reads + W_ih1 dots are phase-known (distinct LDS
//    arrays -> compiler may hoist across the serial h1 chain); each
//    wave's chain is only tanh -> own-LDS RT -> 10-pk dot (~280cyc).

#define Bsz 4096
#define Tn  512
#define Hn  20
#define GB  8                  // batches per block
#define K   8                  // steps per phase
#define RING 16
#define NPH (Tn / K)           // 64 phases
#define XPAD 516
#define NTHREADS 128

typedef float v2 __attribute__((ext_vector_type(2)));

__device__ __forceinline__ float tanh_fast(float v) {
    // tanh(v) = 1 - 2/(exp(2v)+1); v_exp_f32 + v_rcp_f32.
    float e = __expf(2.0f * v);
    return 1.0f - 2.0f * __builtin_amdgcn_rcpf(e + 1.0f);
}

// packed 20-dot: 10 v_pk_fma_f32, two chains
#define DOT20P(acc, accb, W, H) do { \
    acc  = __builtin_elementwise_fma(W##0, H##0, acc);  \
    accb = __builtin_elementwise_fma(W##1, H##1, accb); \
    acc  = __builtin_elementwise_fma(W##2, H##2, acc);  \
    accb = __builtin_elementwise_fma(W##3, H##3, accb); \
    acc  = __builtin_elementwise_fma(W##4, H##4, acc);  \
    accb = __builtin_elementwise_fma(W##5, H##5, accb); \
    acc  = __builtin_elementwise_fma(W##6, H##6, acc);  \
    accb = __builtin_elementwise_fma(W##7, H##7, accb); \
    acc  = __builtin_elementwise_fma(W##8, H##8, acc);  \
    accb = __builtin_elementwise_fma(W##9, H##9, accb); \
} while (0)

#define LOAD_ROWP(W, ptr) \
    v2 W##0, W##1, W##2, W##3, W##4, W##5, W##6, W##7, W##8, W##9; \
    { const float4* _p = (const float4*)(ptr); \
      float4 _t; \
      _t = _p[0]; W##0 = (v2){_t.x, _t.y}; W##1 = (v2){_t.z, _t.w}; \
      _t = _p[1]; W##2 = (v2){_t.x, _t.y}; W##3 = (v2){_t.z, _t.w}; \
      _t = _p[2]; W##4 = (v2){_t.x, _t.y}; W##5 = (v2){_t.z, _t.w}; \
      _t = _p[3]; W##6 = (v2){_t.x, _t.y}; W##7 = (v2){_t.z, _t.w}; \
      _t = _p[4]; W##8 = (v2){_t.x, _t.y}; W##9 = (v2){_t.z, _t.w}; }

#define READ_H(H, base) \
    v2 H##0, H##1, H##2, H##3, H##4, H##5, H##6, H##7, H##8, H##9; \
    { const float4 _a = *(const float4*)((base) + 0);  \
      const float4 _b = *(const float4*)((base) + 4);  \
      const float4 _c = *(const float4*)((base) + 8);  \
      const float4 _d = *(const float4*)((base) + 12); \
      const float4 _e = *(const float4*)((base) + 16); \
      H##0 = (v2){_a.x, _a.y}; H##1 = (v2){_a.z, _a.w}; \
      H##2 = (v2){_b.x, _b.y}; H##3 = (v2){_b.z, _b.w}; \
      H##4 = (v2){_c.x, _c.y}; H##5 = (v2){_c.z, _c.w}; \
      H##6 = (v2){_d.x, _d.y}; H##7 = (v2){_d.z, _d.w}; \
      H##8 = (v2){_e.x, _e.y}; H##9 = (v2){_e.z, _e.w}; }

__global__ __launch_bounds__(NTHREADS)
__attribute__((amdgpu_waves_per_eu(1, 1)))
void rnn2_fused(const float* __restrict__ x,        // [B,T,1]
                const float* __restrict__ hidden,   // [2,B,H]
                const float* __restrict__ W_ih0,    // [H,1]
                const float* __restrict__ W_hh0,    // [H,H]
                const float* __restrict__ b_ih0,    // [H]
                const float* __restrict__ b_hh0,    // [H]
                const float* __restrict__ W_ih1,    // [H,H]
                const float* __restrict__ W_hh1,    // [H,H]
                const float* __restrict__ b_ih1,    // [H]
                const float* __restrict__ b_hh1,    // [H]
                const float* __restrict__ fc_w,     // [1,H]
                const float* __restrict__ fc_b,     // [1]
                float* __restrict__ out)            // [B] ++ [2,B,H] flat
{
    const int tid  = threadIdx.x;
    const int wave = tid >> 6;         // 0 = layer0, 1 = layer1
    const int lane = tid & 63;
    const int g    = lane >> 3;        // batch 0..7
    const int jj   = lane & 7;         // 0..7
    const int r0   = jj;               // row-slot 0
    const int r1   = jj + 8;           // row-slot 1
    const int r2   = (jj + 16 < Hn) ? (jj + 16) : (Hn - 1);  // slot 2 (clamped)
    const int b    = blockIdx.x * GB + g;   // 4096 = 512*8: always valid

    __shared__ float xs[GB][XPAD];         // 16.5 KB
    __shared__ float h0r[RING][GB][Hn];    // h0 ring, 10.24 KB (cross-wave)
    __shared__ float h1s[GB][Hn];          // wave1-private

    // ---- weights: 3 row-slots. wave0: mA=W_hh0 (wB unused but loaded).
    //      wave1: mA=W_ih1, wB=W_hh1.
    const float* mA = (wave == 0) ? W_hh0 : W_ih1;
    LOAD_ROWP(wA0, mA + r0 * Hn)
    LOAD_ROWP(wA1, mA + r1 * Hn)
    LOAD_ROWP(wA2, mA + r2 * Hn)
    LOAD_ROWP(wB0, W_hh1 + r0 * Hn)
    LOAD_ROWP(wB1, W_hh1 + r1 * Hn)
    LOAD_ROWP(wB2, W_hh1 + r2 * Hn)

    const float wih0_0 = W_ih0[r0], wih0_1 = W_ih0[r1], wih0_2 = W_ih0[r2];
    const float bA0 = (wave == 0) ? (b_ih0[r0] + b_hh0[r0]) : (b_ih1[r0] + b_hh1[r0]);
    const float bA1 = (wave == 0) ? (b_ih0[r1] + b_hh0[r1]) : (b_ih1[r1] + b_hh1[r1]);
    const float bA2 = (wave == 0) ? (b_ih0[r2] + b_hh0[r2]) : (b_ih1[r2] + b_hh1[r2]);

    // ---- stage ALL x (128 threads, coalesced float4; exact divisibility)
    {
        const int bB = blockIdx.x * GB;
        #pragma unroll
        for (int r = 0; r < (GB * Tn) / (NTHREADS * 4); ++r) {  // 8 rounds
            const int c  = (r * NTHREADS + tid) * 4;
            const int gg = c >> 9;
            const int t  = c & (Tn - 1);
            float4 v = *(const float4*)(x + (long)(bB + gg) * Tn + t);
            *(float4*)&xs[gg][t] = v;
        }
    }

    // ---- init: h0[-1] -> ring slot 15 (t=0 reads (0-1)&15); h1[-1] -> h1s
    if (wave == 0) {
        h0r[RING - 1][g][r0] = hidden[(long)b * Hn + r0];
        h0r[RING - 1][g][r1] = hidden[(long)b * Hn + r1];
        h0r[RING - 1][g][r2] = hidden[(long)b * Hn + r2];   // dup benign
    } else {
        h1s[g][r0] = hidden[(long)Bsz * Hn + (long)b * Hn + r0];
        h1s[g][r1] = hidden[(long)Bsz * Hn + (long)b * Hn + r1];
        h1s[g][r2] = hidden[(long)Bsz * Hn + (long)b * Hn + r2];
    }
    __syncthreads();

    float k0 = 0.f, k1 = 0.f, k2 = 0.f;   // last-computed values per slot

    // ---- phases: wave0 active k<NPH (steps Kk..Kk+7 -> ring half k&1);
    // wave1 active k>0 (steps K(k-1)..Kk-1, reading the OTHER half).
    for (int k = 0; k <= NPH; ++k) {
        if (wave == 0) {
            if (k < NPH) {
                #pragma unroll
                for (int u = 0; u < K; ++u) {
                    const int t = k * K + u;
                    READ_H(hA, &h0r[(t - 1) & (RING - 1)][g][0])
                    const float xt = xs[g][t];
                    v2 a0 = (v2){fmaf(xt, wih0_0, bA0), 0.f}, a0b = (v2){0.f, 0.f};
                    v2 a1 = (v2){fmaf(xt, wih0_1, bA1), 0.f}, a1b = (v2){0.f, 0.f};
                    v2 a2 = (v2){fmaf(xt, wih0_2, bA2), 0.f}, a2b = (v2){0.f, 0.f};
                    DOT20P(a0, a0b, wA0, hA);
                    DOT20P(a1, a1b, wA1, hA);
                    DOT20P(a2, a2b, wA2, hA);
                    const v2 s0 = a0 + a0b, s1 = a1 + a1b, s2 = a2 + a2b;
                    k0 = tanh_fast(s0.x + s0.y);
                    k1 = tanh_fast(s1.x + s1.y);
                    k2 = tanh_fast(s2.x + s2.y);
                    const int q = t & (RING - 1);
                    h0r[q][g][r0] = k0;
                    h0r[q][g][r1] = k1;
                    h0r[q][g][r2] = k2;   // dup lanes: same value, benign
                }
            }
        } else {
            if (k > 0) {
                #pragma unroll
                for (int u = 0; u < K; ++u) {
                    const int t = (k - 1) * K + u;
                    READ_H(hA, &h0r[t & (RING - 1)][g][0])  // h0[t], pre-phase
                    READ_H(hB, &h1s[g][0])                  // h1[t-1], own
                    v2 a0 = (v2){bA0, 0.f}, a0b = (v2){0.f, 0.f};
                    v2 a1 = (v2){bA1, 0.f}, a1b = (v2){0.f, 0.f};
                    v2 a2 = (v2){bA2, 0.f}, a2b = (v2){0.f, 0.f};
                    v2 c0 = (v2){0.f, 0.f}, c0b = (v2){0.f, 0.f};
                    v2 c1 = (v2){0.f, 0.f}, c1b = (v2){0.f, 0.f};
                    v2 c2 = (v2){0.f, 0.f}, c2b = (v2){0.f, 0.f};
                    DOT20P(a0, a0b, wA0, hA);   // phase-known: hoistable
                    DOT20P(a1, a1b, wA1, hA);
                    DOT20P(a2, a2b, wA2, hA);
                    DOT20P(c0, c0b, wB0, hB);   // serial on h1
                    DOT20P(c1, c1b, wB1, hB);
                    DOT20P(c2, c2b, wB2, hB);
                    const v2 s0 = (a0 + a0b) + (c0 + c0b);
                    const v2 s1 = (a1 + a1b) + (c1 + c1b);
                    const v2 s2 = (a2 + a2b) + (c2 + c2b);
                    k0 = tanh_fast(s0.x + s0.y);
                    k1 = tanh_fast(s1.x + s1.y);
                    k2 = tanh_fast(s2.x + s2.y);
                    h1s[g][r0] = k0;            // h1[t]
                    h1s[g][r1] = k1;
                    h1s[g][r2] = k2;            // dup benign
                }
            }
        }
        if (k < NPH) __syncthreads();   // k is block-uniform
    }

    // ---- outputs (k0/k1/k2 = step-511 values per slot)
    if (wave == 0) {
        out[Bsz + (long)b * Hn + r0] = k0;                    // new_hidden[0]
        out[Bsz + (long)b * Hn + r1] = k1;
        out[Bsz + (long)b * Hn + r2] = k2;                    // dup benign
    } else {
        out[Bsz + (long)Bsz * Hn + (long)b * Hn + r0] = k0;   // new_hidden[1]
        out[Bsz + (long)Bsz * Hn + (long)b * Hn + r1] = k1;
        out[Bsz + (long)Bsz * Hn + (long)b * Hn + r2] = k2;
        if (jj == 0) {                 // fc head: one lane per batch
            LOAD_ROWP(fw, fc_w)
            READ_H(hv, &h1s[g][0])     // own-wave in-order
            v2 aA = (v2){fc_b[0], 0.f};
            v2 aB = (v2){0.f, 0.f};
            DOT20P(aA, aB, fw, hv);
            const v2 s = aA + aB;
            out[b] = s.x + s.y;
        }
    }
}

extern "C" void kernel_launch(void* const* d_in, const int* in_sizes, int n_in,
                              void* d_out, int out_size, void* d_ws, size_t ws_size,
                              hipStream_t stream) {
    const float* x      = (const float*)d_in[0];
    const float* hidden = (const float*)d_in[1];
    const float* W_ih0  = (const float*)d_in[2];
    const float* W_hh0  = (const float*)d_in[3];
    const float* b_ih0  = (const float*)d_in[4];
    const float* b_hh0  = (const float*)d_in[5];
    const float* W_ih1  = (const float*)d_in[6];
    const float* W_hh1  = (const float*)d_in[7];
    const float* b_ih1  = (const float*)d_in[8];
    const float* b_hh1  = (const float*)d_in[9];
    const float* fc_w   = (const float*)d_in[10];
    const float* fc_b   = (const float*)d_in[11];

    rnn2_fused<<<Bsz / GB, NTHREADS, 0, stream>>>(   // 512 blocks = 1024 waves
        x, hidden, W_ih0, W_hh0, b_ih0, b_hh0,
        W_ih1, W_hh1, b_ih1, b_hh1, fc_w, fc_b, (float*)d_out);
}